// Round 10
// baseline (113.253 us; speedup 1.0000x reference)
//
#include <hip/hip_runtime.h>
#include <hip/hip_bf16.h>
#include <math.h>

#define N 2048
#define NC 8

// ws layout:
//   [0, 64)              : double acc[8]          (zeroed by k_prep block 0)
//   [64, 64+128K)        : float2 pack[8][2048]   {s/ln2, A/ln2} packed by k_prep
//   [64+128K, 64+192K)   : int    lohi[8][2048]   (lo | hi<<16, per ORIGINAL row)
//   [64+192K, +4)        : unsigned counter       (ticket for fused finalize)

#if __has_builtin(__builtin_amdgcn_exp2f)
__device__ __forceinline__ float fexp2(float x) { return __builtin_amdgcn_exp2f(x); }
#else
__device__ __forceinline__ float fexp2(float x) { return exp2f(x); }
#endif
#if __has_builtin(__builtin_amdgcn_logf)
__device__ __forceinline__ float flog2(float x) { return __builtin_amdgcn_logf(x); }
#else
__device__ __forceinline__ float flog2(float x) { return log2f(x); }
#endif

#define INV_LN2 1.4426950408889634f
#define LN2_D   0.6931471805599453
#define CLAMP2  (-144.26950408889634f)   /* -100/ln2 : clamp in log2 domain */

// ---------------- Kernel 1: fused A-sum + counting-rank GT + packing ----------
// blocks [0,256):   A[j] = sum_i |s_j - s_i| ; write pack[col][j] = {s,A}/ln2
// blocks [256,512): counting-rank windows -> lohi
__global__ __launch_bounds__(256) void k_prep(const float* __restrict__ logits,
                                              const float* __restrict__ dur,
                                              const int* __restrict__ ev,
                                              float2* __restrict__ pack,
                                              int* __restrict__ lohi,
                                              double* __restrict__ acc,
                                              unsigned* __restrict__ counter) {
    __shared__ float s[N];                   // 8 KB   (asum)
    __shared__ double part[256];             // 2 KB   (asum)
    __shared__ unsigned long long keys[N];   // 16 KB  (sortgt)
    __shared__ int pr[256], pv[256];         // 2 KB   (sortgt)

    int b = blockIdx.x;
    int tid = threadIdx.x;

    if (b == 0) {  // zero accumulators + ticket for k_bce (stream-ordered)
        if (tid < 8) acc[tid] = 0.0;
        else if (tid == 8) counter[0] = 0u;
    }

    if (b < 256) {
        // ---- A-sum, 64 j's per block, 4 i-slices of 512 (f64: exactness) ----
        int col = b >> 5, chunk = b & 31;
        for (int k = 0; k < N / 256; ++k) {
            int i = tid + k * 256;
            s[i] = logits[i * NC + col];
        }
        __syncthreads();
        int jl = tid & 63, slice = tid >> 6;
        int j = chunk * 64 + jl;
        float sj = s[j];
        int base = slice * 512;
        double a0 = 0.0, a1 = 0.0, a2 = 0.0, a3 = 0.0;
        #pragma unroll 2
        for (int i = 0; i < 512; i += 4) {
            a0 += (double)fabsf(sj - s[base + i]);
            a1 += (double)fabsf(sj - s[base + i + 1]);
            a2 += (double)fabsf(sj - s[base + i + 2]);
            a3 += (double)fabsf(sj - s[base + i + 3]);
        }
        part[tid] = (a0 + a1) + (a2 + a3);
        __syncthreads();
        if (tid < 64) {
            double v = ((part[tid] + part[tid + 64]) + part[tid + 128]) + part[tid + 192];
            pack[col * N + j] = make_float2(sj * INV_LN2, (float)v * INV_LN2);
        }
    } else {
        // ---- counting-rank GT windows ----
        // key = (dur_bits<<32)|(i<<1)|e : ascending u64 == stable ascending by d
        int b2 = b - 256;
        int col = b2 >> 5, chunk = b2 & 31;
        for (int k = 0; k < N / 256; ++k) {
            int i = tid + k * 256;
            unsigned int db = __float_as_uint(dur[i * NC + col]);  // dur in [0,1)
            int e = ev[i * NC + col];
            keys[i] = ((unsigned long long)db << 32) | (unsigned int)((i << 1) | e);
        }
        __syncthreads();
        int jl = tid & 63, slice = tid >> 6;
        int j = chunk * 64 + jl;
        unsigned long long kj = keys[j];
        int base = slice * 512;
        int rank = 0, evlt = 0;
        #pragma unroll 4
        for (int i = 0; i < 512; ++i) {
            unsigned long long ki = keys[base + i];
            int lt = (ki < kj) ? 1 : 0;
            rank += lt;
            evlt += lt & (int)(ki & 1ull);
        }
        pr[tid] = rank;
        pv[tid] = evlt;
        __syncthreads();
        if (tid < 64) {
            int r = ((pr[tid] + pr[tid + 64]) + pr[tid + 128]) + pr[tid + 192];
            int v = ((pv[tid] + pv[tid + 64]) + pv[tid + 128]) + pv[tid + 192];
            int e = (int)(kj & 1ull);
            int hi = e ? (r + 1) : N;
            lohi[col * N + j] = v | (hi << 16);
        }
    }
}

// ---------------- Kernel 2: softmax+BCE, no-LDS, single final butterfly -------
// m0-frame incremental exp (r9). New in r10:
//  * NO LDS staging: lane fragment pack[col*N + lane + 64k] is already
//    coalesced (8 B/lane) and L2-resident (16 KB/col shared by 128 blocks) —
//    global loads go straight to the register cache; zero barriers pre-compute.
//  * single final butterfly: y_c is known before pass 3, so accumulate
//    r = sum_c (a1_c + y_c*a2_c) per lane and reduce ONCE (78 -> 36 shuffle
//    steps/wave).
//  * LDS = 32 B (bsum only) — no LDS occupancy term.
// Plain __launch_bounds__(256) ONLY (min-waves clamps / 1024-thread blocks
// collapse the VGPR budget and spill: r3/r4/r6). Target VGPR <= ~120.
__global__ __launch_bounds__(256) void k_bce(const float2* __restrict__ pack,
                                             const int* __restrict__ lohi,
                                             double* __restrict__ acc,
                                             unsigned* __restrict__ counter,
                                             float* __restrict__ out) {
    int col = blockIdx.x >> 7;   // 0..7
    int rg  = blockIdx.x & 127;  // 0..127 (16 rows each)
    __shared__ double bsum[4];
    int tid = threadIdx.x;
    int wave = tid >> 6, lane = tid & 63;

    int row0 = (rg << 4) + (wave << 2);
    float sc0 = (float)(N - 1 - 2 * row0);

    // prefetch GT windows (latency overlaps the fragment loads)
    int lh[4];
    #pragma unroll
    for (int c = 0; c < 4; ++c) lh[c] = lohi[col * N + row0 + c];

    // global -> register cache, coalesced dwordx2 loads (L2-hit after 1st use)
    const float2* pc = pack + (size_t)col * N;
    float sv[32], tb[32];
    #pragma unroll
    for (int k = 0; k < 32; ++k) {
        float2 v = pc[lane + (k << 6)];
        sv[k] = v.x;                     // s/ln2
        tb[k] = fmaf(sc0, v.x, -v.y);    // row-0 score (log2 units)
    }

    // pass 1: max of row 0 ONLY (m0 frame)
    float m = -INFINITY;
    #pragma unroll
    for (int k = 0; k < 32; ++k) m = fmaxf(m, tb[k]);
    #pragma unroll
    for (int off = 32; off > 0; off >>= 1)
        m = fmaxf(m, __shfl_xor(m, off, 64));

    // pass 2: se_c = sum_j 2^(t_c - m0); rows 1..3 by incremental multiply
    float se0 = 0.0f, se1 = 0.0f, se2 = 0.0f, se3 = 0.0f;
    #pragma unroll
    for (int k = 0; k < 32; ++k) {
        float g = fexp2(-(sv[k] + sv[k]));
        float E = fexp2(tb[k] - m);
        se0 += E; E *= g;
        se1 += E; E *= g;
        se2 += E; E *= g;
        se3 += E;
    }
    #pragma unroll
    for (int off = 32; off > 0; off >>= 1) {
        se0 += __shfl_xor(se0, off, 64);
        se1 += __shfl_xor(se1, off, 64);
        se2 += __shfl_xor(se2, off, 64);
        se3 += __shfl_xor(se3, off, 64);
    }
    float se[4] = {se0, se1, se2, se3};

    float C2v[4], yv[4];
    unsigned lo[4], wl[4];
    double rbase = 0.0;
    #pragma unroll
    for (int c = 0; c < 4; ++c) {
        float L2 = flog2(se[c]);
        rbase -= 2048.0 * (double)L2;         // -n*L2 term of sum l1
        C2v[c] = CLAMP2 + L2;                 // clamp threshold in (t-m0) units
        lo[c] = (unsigned)(lh[c] & 0xffff);
        wl[c] = (unsigned)((lh[c] >> 16) & 0xffff) - lo[c];
        yv[c] = 1.0f / (float)wl[c];
    }

    // pass 3: r = sum_c (a1_c + y_c*a2_c), single per-lane accumulator pair set
    float a1[4] = {0.0f, 0.0f, 0.0f, 0.0f};
    float a2[4] = {0.0f, 0.0f, 0.0f, 0.0f};
    #pragma unroll
    for (int k = 0; k < 32; ++k) {
        float tsv = sv[k] + sv[k];
        float g = fexp2(-tsv);
        float x = tb[k] - m;
        float E = fexp2(x);
        int j = lane + (k << 6);
        #pragma unroll
        for (int c = 0; c < 4; ++c) {
            float mx2 = fmaxf(flog2(se[c] - E), C2v[c]);  // se >= E (RN monotone)
            a1[c] += mx2;
            float mx1 = fmaxf(x, C2v[c]);
            float w = ((unsigned)(j - lo[c]) < wl[c]) ? (mx1 - mx2) : 0.0f;
            a2[c] += w;
            E *= g;     // -> E_{c+1}
            x -= tsv;   // -> x_{c+1}
        }
    }
    // fold rows with y BEFORE the reduction: one butterfly instead of eight
    float r = 0.0f;
    #pragma unroll
    for (int c = 0; c < 4; ++c) r += fmaf(yv[c], a2[c], a1[c]);
    #pragma unroll
    for (int off = 32; off > 0; off >>= 1)
        r += __shfl_xor(r, off, 64);

    // block combine -> 1 atomic/block -> ticket finalize in last block
    if (lane == 0) bsum[wave] = rbase + (double)r;
    __syncthreads();
    if (tid == 0) {
        double tot = (bsum[0] + bsum[1]) + (bsum[2] + bsum[3]);
        atomicAdd(&acc[col], LN2_D * tot);
        __threadfence();
        unsigned old = atomicAdd(counter, 1u);
        if (old == (unsigned)(NC * 128 - 1)) {  // last of 1024 blocks
            __threadfence();
            float ssum = 0.0f;
            int cnt = 0;
            for (int c = 0; c < NC; ++c) {
                double av2 = atomicAdd(&acc[c], 0.0);  // device-scope read
                float lc = (float)(-av2 / ((double)N * (double)N));
                if (lc > 0.0f) { ssum += lc; cnt++; }
            }
            out[0] = ssum / (float)(cnt > 0 ? cnt : 1);
        }
    }
}

extern "C" void kernel_launch(void* const* d_in, const int* in_sizes, int n_in,
                              void* d_out, int out_size, void* d_ws, size_t ws_size,
                              hipStream_t stream) {
    const float* logits    = (const float*)d_in[0];
    const int*   events    = (const int*)d_in[1];
    const float* durations = (const float*)d_in[2];
    float* out = (float*)d_out;

    char* ws = (char*)d_ws;
    double*   acc     = (double*)ws;
    float2*   pack    = (float2*)(ws + 64);
    int*      lohi    = (int*)(ws + 64 + (size_t)NC * N * sizeof(float2));
    unsigned* counter = (unsigned*)(ws + 64 + (size_t)NC * N * (sizeof(float2) + sizeof(int)));

    k_prep<<<dim3(512), 256, 0, stream>>>(logits, durations, events, pack, lohi, acc, counter);
    k_bce<<<dim3(NC * 128), 256, 0, stream>>>(pack, lohi, acc, counter, out);
}

// Round 11
// 101.421 us; speedup vs baseline: 1.1167x; 1.1167x over previous
//
#include <hip/hip_runtime.h>
#include <hip/hip_bf16.h>
#include <math.h>

#define N 2048
#define NC 8

// ws layout:
//   [0, 64)              : double acc[8]          (zeroed by k_prep block 0)
//   [64, 64+128K)        : float2 pack[8][2048]   {s/ln2, A/ln2} packed by k_prep
//   [64+128K, 64+192K)   : int    lohi[8][2048]   (lo | hi<<16, per ORIGINAL row)
//   [64+192K, +4)        : unsigned counter       (ticket for fused finalize)

#if __has_builtin(__builtin_amdgcn_exp2f)
__device__ __forceinline__ float fexp2(float x) { return __builtin_amdgcn_exp2f(x); }
#else
__device__ __forceinline__ float fexp2(float x) { return exp2f(x); }
#endif
#if __has_builtin(__builtin_amdgcn_logf)
__device__ __forceinline__ float flog2(float x) { return __builtin_amdgcn_logf(x); }
#else
__device__ __forceinline__ float flog2(float x) { return log2f(x); }
#endif

#define INV_LN2 1.4426950408889634f
#define LN2_D   0.6931471805599453
#define CLAMP2  (-144.26950408889634f)   /* -100/ln2 : clamp in log2 domain */

// ---------------- Kernel 1: fused A-sum + counting-rank GT + packing ----------
// blocks [0,256):   A[j] = sum_i |s_j - s_i| ; write pack[col][j] = {s,A}/ln2
// blocks [256,512): counting-rank windows -> lohi
__global__ __launch_bounds__(256) void k_prep(const float* __restrict__ logits,
                                              const float* __restrict__ dur,
                                              const int* __restrict__ ev,
                                              float2* __restrict__ pack,
                                              int* __restrict__ lohi,
                                              double* __restrict__ acc,
                                              unsigned* __restrict__ counter) {
    __shared__ float s[N];                   // 8 KB   (asum)
    __shared__ double part[256];             // 2 KB   (asum)
    __shared__ unsigned long long keys[N];   // 16 KB  (sortgt)
    __shared__ int pr[256], pv[256];         // 2 KB   (sortgt)

    int b = blockIdx.x;
    int tid = threadIdx.x;

    if (b == 0) {  // zero accumulators + ticket for k_bce (stream-ordered)
        if (tid < 8) acc[tid] = 0.0;
        else if (tid == 8) counter[0] = 0u;
    }

    if (b < 256) {
        // ---- A-sum, 64 j's per block, 4 i-slices of 512 (f64: exactness) ----
        int col = b >> 5, chunk = b & 31;
        for (int k = 0; k < N / 256; ++k) {
            int i = tid + k * 256;
            s[i] = logits[i * NC + col];
        }
        __syncthreads();
        int jl = tid & 63, slice = tid >> 6;
        int j = chunk * 64 + jl;
        float sj = s[j];
        int base = slice * 512;
        double a0 = 0.0, a1 = 0.0, a2 = 0.0, a3 = 0.0;
        #pragma unroll 2
        for (int i = 0; i < 512; i += 4) {
            a0 += (double)fabsf(sj - s[base + i]);
            a1 += (double)fabsf(sj - s[base + i + 1]);
            a2 += (double)fabsf(sj - s[base + i + 2]);
            a3 += (double)fabsf(sj - s[base + i + 3]);
        }
        part[tid] = (a0 + a1) + (a2 + a3);
        __syncthreads();
        if (tid < 64) {
            double v = ((part[tid] + part[tid + 64]) + part[tid + 128]) + part[tid + 192];
            pack[col * N + j] = make_float2(sj * INV_LN2, (float)v * INV_LN2);
        }
    } else {
        // ---- counting-rank GT windows ----
        // key = (dur_bits<<32)|(i<<1)|e : ascending u64 == stable ascending by d
        int b2 = b - 256;
        int col = b2 >> 5, chunk = b2 & 31;
        for (int k = 0; k < N / 256; ++k) {
            int i = tid + k * 256;
            unsigned int db = __float_as_uint(dur[i * NC + col]);  // dur in [0,1)
            int e = ev[i * NC + col];
            keys[i] = ((unsigned long long)db << 32) | (unsigned int)((i << 1) | e);
        }
        __syncthreads();
        int jl = tid & 63, slice = tid >> 6;
        int j = chunk * 64 + jl;
        unsigned long long kj = keys[j];
        int base = slice * 512;
        int rank = 0, evlt = 0;
        #pragma unroll 4
        for (int i = 0; i < 512; ++i) {
            unsigned long long ki = keys[base + i];
            int lt = (ki < kj) ? 1 : 0;
            rank += lt;
            evlt += lt & (int)(ki & 1ull);
        }
        pr[tid] = rank;
        pv[tid] = evlt;
        __syncthreads();
        if (tid < 64) {
            int r = ((pr[tid] + pr[tid + 64]) + pr[tid + 128]) + pr[tid + 192];
            int v = ((pv[tid] + pv[tid + 64]) + pv[tid + 128]) + pv[tid + 192];
            int e = (int)(kj & 1ull);
            int hi = e ? (r + 1) : N;
            lohi[col * N + j] = v | (hi << 16);
        }
    }
}

// ---------------- Kernel 2: softmax+BCE, m0-frame incremental exp -------------
// Structure = r9 (LDS staging restored: it is a register-pressure tool — r10's
// direct-global variant hit VGPR 132 > 128 cliff and regressed to 59 us) plus
// r10's one good idea: fold a1_c + y_c*a2_c per-lane BEFORE reducing, so pass 3
// runs ONE butterfly instead of eight.
// Wave handles 4 consecutive rows. t_c[j] = tb[j] - 2c*s_j; in the row-0 max
// frame E_c = E_{c-1}*g_j, g_j = 2^(-2 s_j): rows 1..3 need no max, no exp.
// Plain __launch_bounds__(256) ONLY (clamps/1024-blocks spill: r3/r4/r6).
__global__ __launch_bounds__(256) void k_bce(const float2* __restrict__ pack,
                                             const int* __restrict__ lohi,
                                             double* __restrict__ acc,
                                             unsigned* __restrict__ counter,
                                             float* __restrict__ out) {
    int col = blockIdx.x >> 7;   // 0..7
    int rg  = blockIdx.x & 127;  // 0..127 (16 rows each)
    __shared__ union SU {
        float2 sa[N];            // staged {s/ln2, A/ln2} — dead after reg cache
        float4 sa4[N / 2];
        double bsum[4];          // block reduction buffer (aliases sa[0..3])
    } u;                         // exactly 16384 B
    int tid = threadIdx.x;
    int wave = tid >> 6, lane = tid & 63;

    // fully-coalesced staging: 16 KB contiguous, float4
    const float4* p4 = (const float4*)(pack + (size_t)col * N);
    #pragma unroll
    for (int k = 0; k < 4; ++k) {
        int i = tid + (k << 8);
        u.sa4[i] = p4[i];
    }
    __syncthreads();

    int row0 = (rg << 4) + (wave << 2);
    float sc0 = (float)(N - 1 - 2 * row0);

    // one-time LDS -> register cache: sv = s/ln2, tb = row-0 scores
    float sv[32], tb[32];
    #pragma unroll
    for (int k = 0; k < 32; ++k) {
        float2 v = u.sa[lane + (k << 6)];
        sv[k] = v.x;
        tb[k] = fmaf(sc0, v.x, -v.y);
    }
    __syncthreads();   // sa dead; u.bsum written below

    // prefetch GT windows (latency overlaps pass 1/2)
    int lh[4];
    #pragma unroll
    for (int c = 0; c < 4; ++c) lh[c] = lohi[col * N + row0 + c];

    // pass 1: max of row 0 ONLY (m0 frame)
    float m = -INFINITY;
    #pragma unroll
    for (int k = 0; k < 32; ++k) m = fmaxf(m, tb[k]);
    #pragma unroll
    for (int off = 32; off > 0; off >>= 1)
        m = fmaxf(m, __shfl_xor(m, off, 64));

    // pass 2: se_c = sum_j 2^(t_c - m0); rows 1..3 by incremental multiply
    float se0 = 0.0f, se1 = 0.0f, se2 = 0.0f, se3 = 0.0f;
    #pragma unroll
    for (int k = 0; k < 32; ++k) {
        float g = fexp2(-(sv[k] + sv[k]));
        float E = fexp2(tb[k] - m);
        se0 += E; E *= g;
        se1 += E; E *= g;
        se2 += E; E *= g;
        se3 += E;
    }
    #pragma unroll
    for (int off = 32; off > 0; off >>= 1) {
        se0 += __shfl_xor(se0, off, 64);
        se1 += __shfl_xor(se1, off, 64);
        se2 += __shfl_xor(se2, off, 64);
        se3 += __shfl_xor(se3, off, 64);
    }
    float se[4] = {se0, se1, se2, se3};

    float C2v[4], yv[4];
    unsigned lo[4], wl[4];
    double rbase = 0.0;
    #pragma unroll
    for (int c = 0; c < 4; ++c) {
        float L2 = flog2(se[c]);
        rbase -= 2048.0 * (double)L2;         // -n*L2 term of sum l1
        C2v[c] = CLAMP2 + L2;                 // clamp threshold in (t-m0) units
        lo[c] = (unsigned)(lh[c] & 0xffff);
        wl[c] = (unsigned)((lh[c] >> 16) & 0xffff) - lo[c];
        yv[c] = 1.0f / (float)wl[c];
    }

    // pass 3: a1_c = sum max(log2(se_c - E_c), C2_c); a2_c = windowed (mx1-mx2)
    float a1[4] = {0.0f, 0.0f, 0.0f, 0.0f};
    float a2[4] = {0.0f, 0.0f, 0.0f, 0.0f};
    #pragma unroll
    for (int k = 0; k < 32; ++k) {
        float tsv = sv[k] + sv[k];
        float g = fexp2(-tsv);
        float x = tb[k] - m;
        float E = fexp2(x);
        int j = lane + (k << 6);
        #pragma unroll
        for (int c = 0; c < 4; ++c) {
            float mx2 = fmaxf(flog2(se[c] - E), C2v[c]);  // se >= E (RN monotone)
            a1[c] += mx2;
            float mx1 = fmaxf(x, C2v[c]);
            float w = ((unsigned)(j - lo[c]) < wl[c]) ? (mx1 - mx2) : 0.0f;
            a2[c] += w;
            E *= g;     // -> E_{c+1}
            x -= tsv;   // -> x_{c+1}
        }
    }
    // fold rows with y BEFORE the reduction: one butterfly instead of eight
    float r = 0.0f;
    #pragma unroll
    for (int c = 0; c < 4; ++c) r += fmaf(yv[c], a2[c], a1[c]);
    #pragma unroll
    for (int off = 32; off > 0; off >>= 1)
        r += __shfl_xor(r, off, 64);

    // block combine -> 1 atomic/block -> ticket finalize in last block
    if (lane == 0) u.bsum[wave] = rbase + (double)r;
    __syncthreads();
    if (tid == 0) {
        double tot = (u.bsum[0] + u.bsum[1]) + (u.bsum[2] + u.bsum[3]);
        atomicAdd(&acc[col], LN2_D * tot);
        __threadfence();
        unsigned old = atomicAdd(counter, 1u);
        if (old == (unsigned)(NC * 128 - 1)) {  // last of 1024 blocks
            __threadfence();
            float ssum = 0.0f;
            int cnt = 0;
            for (int c = 0; c < NC; ++c) {
                double av2 = atomicAdd(&acc[c], 0.0);  // device-scope read
                float lc = (float)(-av2 / ((double)N * (double)N));
                if (lc > 0.0f) { ssum += lc; cnt++; }
            }
            out[0] = ssum / (float)(cnt > 0 ? cnt : 1);
        }
    }
}

extern "C" void kernel_launch(void* const* d_in, const int* in_sizes, int n_in,
                              void* d_out, int out_size, void* d_ws, size_t ws_size,
                              hipStream_t stream) {
    const float* logits    = (const float*)d_in[0];
    const int*   events    = (const int*)d_in[1];
    const float* durations = (const float*)d_in[2];
    float* out = (float*)d_out;

    char* ws = (char*)d_ws;
    double*   acc     = (double*)ws;
    float2*   pack    = (float2*)(ws + 64);
    int*      lohi    = (int*)(ws + 64 + (size_t)NC * N * sizeof(float2));
    unsigned* counter = (unsigned*)(ws + 64 + (size_t)NC * N * (sizeof(float2) + sizeof(int)));

    k_prep<<<dim3(512), 256, 0, stream>>>(logits, durations, events, pack, lohi, acc, counter);
    k_bce<<<dim3(NC * 128), 256, 0, stream>>>(pack, lohi, acc, counter, out);
}